// Round 7
// baseline (300.823 us; speedup 1.0000x reference)
//
#include <hip/hip_runtime.h>
#include <hip/hip_bf16.h>

#define HH   64
#define H2   128
#define VOC  64
#define LSEQ 2048

typedef float f2 __attribute__((ext_vector_type(2)));
struct K2 { f2 a, b; };
__device__ __forceinline__ K2 as2(float4 q) { return __builtin_bit_cast(K2, q); }

// ---------------------------------------------------------------------------
// Kernel 1: collapse embed -> FFN -> LN -> {kn, v, q} projections into
// per-token tables (VOCAB=64 entries of H=64 floats each).  (unchanged)
// ---------------------------------------------------------------------------
__global__ __launch_bounds__(128) void build_tables(
    const float* __restrict__ embed, const float* __restrict__ w1, const float* __restrict__ b1,
    const float* __restrict__ w2, const float* __restrict__ b2,
    const float* __restrict__ ln_g, const float* __restrict__ ln_b,
    const float* __restrict__ wk, const float* __restrict__ wv, const float* __restrict__ wq,
    float* __restrict__ kn_t, float* __restrict__ v_t, float* __restrict__ q_t)
{
    const int tok = blockIdx.x;
    const int tid = threadIdx.x;
    __shared__ float e_lds[HH];
    __shared__ float h_lds[H2];
    __shared__ float hs_lds[HH];

    if (tid < HH) e_lds[tid] = embed[tok * HH + tid];
    __syncthreads();

    {
        float s = b1[tid];
        #pragma unroll 8
        for (int i = 0; i < HH; ++i) s = fmaf(e_lds[i], w1[i * H2 + tid], s);
        h_lds[tid] = fmaxf(s, 0.f);
    }
    __syncthreads();

    if (tid < HH) {
        float f = b2[tid];
        #pragma unroll 8
        for (int j = 0; j < H2; ++j) f = fmaf(h_lds[j], w2[j * HH + tid], f);
        float x = e_lds[tid] + f;
        float sum = x, sq = x * x;
        #pragma unroll
        for (int m = 1; m < 64; m <<= 1) { sum += __shfl_xor(sum, m); sq += __shfl_xor(sq, m); }
        float mu  = sum * (1.f / HH);
        float var = sq * (1.f / HH) - mu * mu;
        hs_lds[tid] = (x - mu) * rsqrtf(var + 1e-5f) * ln_g[tid] + ln_b[tid];
    }
    __syncthreads();

    if (tid < HH) {
        float k = 0.f, v = 0.f, q = 0.f;
        #pragma unroll 8
        for (int j = 0; j < HH; ++j) {
            float h = hs_lds[j];
            k = fmaf(h, wk[j * HH + tid], k);
            v = fmaf(h, wv[j * HH + tid], v);
            q = fmaf(h, wq[j * HH + tid], q);
        }
        float kk = k * k;
        #pragma unroll
        for (int m = 1; m < 64; m <<= 1) kk += __shfl_xor(kk, m);
        float kn = k / fmaxf(sqrtf(kk), 1e-12f);
        kn_t[tok * HH + tid] = kn;
        v_t [tok * HH + tid] = v;
        q_t [tok * HH + tid] = q;
    }
}

// ---------------------------------------------------------------------------
// Kernel 1b: W[a][b] = kn_a . kn_b  (64x64 token-pair dot table, unchanged)
// ---------------------------------------------------------------------------
__global__ __launch_bounds__(64) void build_w(
    const float* __restrict__ kn_t, float* __restrict__ w_t)
{
    const int a = blockIdx.x, b = threadIdx.x;
    __shared__ float ka[HH];
    ka[b] = kn_t[a * HH + b];
    __syncthreads();
    const float4* kav = (const float4*)ka;
    const float4* kbv = (const float4*)(kn_t + b * HH);
    float4 s = {0.f, 0.f, 0.f, 0.f};
    #pragma unroll
    for (int j = 0; j < 16; ++j) {
        float4 x = kav[j], y = kbv[j];
        s.x = fmaf(x.x, y.x, s.x); s.y = fmaf(x.y, y.y, s.y);
        s.z = fmaf(x.z, y.z, s.z); s.w = fmaf(x.w, y.w, s.w);
    }
    w_t[a * VOC + b] = (s.x + s.y) + (s.z + s.w);
}

// ---------------------------------------------------------------------------
// Kernel 2: lag-1 WY scan.  Overhead-minimized iteration:
//  - K kept as float4 (raw ds_read_b128 payload); f2 views via bit_cast
//    (adjacent-register subviews, no repack movs)
//  - tokens read straight from global with uniform address (scalar-load
//    eligible), 8-slot compile-time rotating array, 10-iter lead
//  - K/v/w prefetched 6 iters ahead (slot (u+6)&7), consumed at (u+1)&7
// ---------------------------------------------------------------------------
__device__ __forceinline__ float quad_sum(float p) {
    int q = __builtin_amdgcn_mov_dpp(__builtin_bit_cast(int, p), 0xB1, 0xF, 0xF, true);
    p += __builtin_bit_cast(float, q);
    q = __builtin_amdgcn_mov_dpp(__builtin_bit_cast(int, p), 0x4E, 0xF, 0xF, true);
    p += __builtin_bit_cast(float, q);
    return p;
}

// BODY(u, PF): iteration n ≡ u (mod 8) of the scan (computes d for step n+1,
// applies pending update for step n).  PF=1: also prefetch token n+10.
#define BODY(u, PF)                                                          \
{                                                                            \
    const int sp = ((u) + 6) & 7;                                            \
    const int sc = ((u) + 1) & 7;                                            \
    if (PF) { int ix = nb + (u) + 10;                                        \
              Tq[((u) + 2) & 7] = seq_b[ix < LSEQ ? ix : LSEQ - 1]; }        \
    const int th = Tq[((u) + 6) & 7];   /* token n+6 */                      \
    const int tl = Tq[((u) + 5) & 7];   /* token n+5 */                      \
    const float4* kp = kn4 + th * 16 + j0q;                                  \
    Kb[sp][0] = kp[0]; Kb[sp][1] = kp[1]; Kb[sp][2] = kp[2]; Kb[sp][3] = kp[3]; \
    vb[sp] = v_lds[th * HH + i];                                             \
    wb[sp] = w_lds[tl * VOC + th];                                           \
    /* rawp = M_{n-1} . k_{n+1} (reads M2 before the update below) */        \
    K2 a0 = as2(Kb[sc][0]), a1 = as2(Kb[sc][1]);                             \
    K2 a2 = as2(Kb[sc][2]), a3 = as2(Kb[sc][3]);                             \
    f2 c0 = M2[0] * a0.a + M2[4] * a2.a;                                     \
    f2 c1 = M2[1] * a0.b + M2[5] * a2.b;                                     \
    f2 c2 = M2[2] * a1.a + M2[6] * a3.a;                                     \
    f2 c3 = M2[3] * a1.b + M2[7] * a3.b;                                     \
    /* deferred rank-1 update with OLD dP: M <- M + d_n k_n^T */             \
    K2 u0 = as2(Kb[(u)][0]), u1 = as2(Kb[(u)][1]);                           \
    K2 u2 = as2(Kb[(u)][2]), u3 = as2(Kb[(u)][3]);                           \
    f2 d2v = {dP, dP};                                                       \
    M2[0] += d2v * u0.a; M2[1] += d2v * u0.b;                                \
    M2[2] += d2v * u1.a; M2[3] += d2v * u1.b;                                \
    M2[4] += d2v * u2.a; M2[5] += d2v * u2.b;                                \
    M2[6] += d2v * u3.a; M2[7] += d2v * u3.b;                                \
    f2 cc = (c0 + c1) + (c2 + c3);                                           \
    float rawp = quad_sum(cc[0] + cc[1]);                                    \
    dP = vb[sc] - fmaf(dP, wb[sc], rawp);                                    \
}

__global__ __launch_bounds__(256) void delta_scan(
    const int* __restrict__ seq,
    const float* __restrict__ kn_t, const float* __restrict__ v_t, const float* __restrict__ q_t,
    const float* __restrict__ w_t,
    const float* __restrict__ wrp, const float* __restrict__ brp,
    const float* __restrict__ wout, const float* __restrict__ bout,
    float* __restrict__ out)
{
    __shared__ __align__(64) float kn_lds[VOC * HH];
    __shared__ __align__(64) float v_lds[VOC * HH];
    __shared__ __align__(64) float w_lds[VOC * VOC];
    __shared__ float r_lds[HH];
    __shared__ float t_lds[HH];

    const int b   = blockIdx.x;
    const int tid = threadIdx.x;
    const int* __restrict__ seq_b = seq + (long)b * LSEQ;

    // cooperative staging: kn/v/W tables (3 x 16KB)
    {
        const float4* s1 = (const float4*)kn_t; float4* d1 = (float4*)kn_lds;
        const float4* s2 = (const float4*)v_t;  float4* d2 = (float4*)v_lds;
        const float4* s4 = (const float4*)w_t;  float4* d4 = (float4*)w_lds;
        #pragma unroll
        for (int r = 0; r < 4; ++r) {
            d1[tid + 256 * r] = s1[tid + 256 * r];
            d2[tid + 256 * r] = s2[tid + 256 * r];
            d4[tid + 256 * r] = s4[tid + 256 * r];
        }
    }
    __syncthreads();

    const int i   = tid >> 2;          // M row this thread contributes to
    const int j0  = (tid & 3) * 16;    // column slice base
    const int j0q = j0 >> 2;           // float4 index offset
    const float4* kn4 = (const float4*)kn_lds;

    f2 M2[8];
    #pragma unroll
    for (int n = 0; n < 8; ++n) M2[n] = (f2){0.f, 0.f};

    float4 Kb[8][4];
    float  vb[8], wb[8];
    int    Tq[8];

    // ---- prologue: K/v/w slots for steps 0..5; tokens 5..9 into Tq.
    const int t0 = seq_b[0], t1 = seq_b[1], t2 = seq_b[2];
    const int t3 = seq_b[3], t4 = seq_b[4], t5 = seq_b[5];
    Tq[5] = t5;        Tq[6] = seq_b[6];  Tq[7] = seq_b[7];
    Tq[0] = seq_b[8];  Tq[1] = seq_b[9];
    {
        const int pt[6] = {t0, t1, t2, t3, t4, t5};
        #pragma unroll
        for (int s = 0; s < 6; ++s) {
            const float4* kp = kn4 + pt[s] * 16 + j0q;
            Kb[s][0] = kp[0]; Kb[s][1] = kp[1]; Kb[s][2] = kp[2]; Kb[s][3] = kp[3];
        }
        #pragma unroll
        for (int s = 1; s < 6; ++s) {
            vb[s] = v_lds[pt[s] * HH + i];
            wb[s] = w_lds[pt[s - 1] * VOC + pt[s]];
        }
    }
    float dP = v_lds[t0 * HH + i];   // d_0 = v_0  (M_{-1} = 0)

    // ---- main loop: iters n = 0..2045 process steps 1..2046.
    int nb = 0;
    for (int g = 0; g < 255; ++g) {
        BODY(0,1) BODY(1,1) BODY(2,1) BODY(3,1)
        BODY(4,1) BODY(5,1) BODY(6,1) BODY(7,1)
        nb += 8;
    }
    BODY(0,0) BODY(1,0) BODY(2,0) BODY(3,0) BODY(4,0) BODY(5,0)  // n=2040..2045

    // final pending update: M += d_2046 k_2046^T  (slot 2046&7 = 6)
    {
        K2 u0 = as2(Kb[6][0]), u1 = as2(Kb[6][1]);
        K2 u2 = as2(Kb[6][2]), u3 = as2(Kb[6][3]);
        f2 d2v = {dP, dP};
        M2[0] += d2v * u0.a; M2[1] += d2v * u0.b;
        M2[2] += d2v * u1.a; M2[3] += d2v * u1.b;
        M2[4] += d2v * u2.a; M2[5] += d2v * u2.b;
        M2[6] += d2v * u3.a; M2[7] += d2v * u3.b;
    }

    // r_i = sum_j M[i][j] * q_j  with q = q_table[last token]
    {
        const int qtok = seq_b[LSEQ - 1];
        const float* qrow = q_t + (long)qtok * HH + j0;
        f2 a0 = (f2){0.f, 0.f}, a1 = (f2){0.f, 0.f};
        #pragma unroll
        for (int n = 0; n < 4; ++n) {
            f2 q0 = (f2){qrow[2*n],     qrow[2*n + 1]};
            f2 q1 = (f2){qrow[2*n + 8], qrow[2*n + 9]};
            a0 += M2[n]     * q0;
            a1 += M2[n + 4] * q1;
        }
        f2 a = a0 + a1;
        float p = quad_sum(a[0] + a[1]);
        if ((tid & 3) == 0) r_lds[i] = p;
    }
    __syncthreads();

    // t = r @ wrp + brp
    if (tid < HH) {
        float s = brp[tid];
        #pragma unroll 8
        for (int ii = 0; ii < HH; ++ii) s = fmaf(r_lds[ii], wrp[ii * HH + tid], s);
        t_lds[tid] = s;
    }
    __syncthreads();

    // out = t @ wout + bout
    if (tid < HH) {
        float s = bout[tid];
        #pragma unroll 8
        for (int h = 0; h < HH; ++h) s = fmaf(t_lds[h], wout[h * VOC + tid], s);
        out[(long)b * VOC + tid] = s;
    }
}

extern "C" void kernel_launch(void* const* d_in, const int* in_sizes, int n_in,
                              void* d_out, int out_size, void* d_ws, size_t ws_size,
                              hipStream_t stream)
{
    const int*   seq   = (const int*)  d_in[0];
    const float* embed = (const float*)d_in[1];
    const float* w1    = (const float*)d_in[2];
    const float* b1    = (const float*)d_in[3];
    const float* w2    = (const float*)d_in[4];
    const float* b2    = (const float*)d_in[5];
    const float* ln_g  = (const float*)d_in[6];
    const float* ln_b  = (const float*)d_in[7];
    const float* wk    = (const float*)d_in[8];
    const float* wv    = (const float*)d_in[9];
    const float* wq    = (const float*)d_in[10];
    const float* wrp   = (const float*)d_in[11];
    const float* brp   = (const float*)d_in[12];
    const float* wout  = (const float*)d_in[13];
    const float* bout  = (const float*)d_in[14];
    float* out = (float*)d_out;

    float* kn_t = (float*)d_ws;
    float* v_t  = kn_t + VOC * HH;
    float* q_t  = v_t  + VOC * HH;
    float* w_t  = q_t  + VOC * HH;

    const int B = in_sizes[0] / LSEQ;   // 256

    hipLaunchKernelGGL(build_tables, dim3(VOC), dim3(H2), 0, stream,
                       embed, w1, b1, w2, b2, ln_g, ln_b, wk, wv, wq,
                       kn_t, v_t, q_t);
    hipLaunchKernelGGL(build_w, dim3(VOC), dim3(HH), 0, stream, kn_t, w_t);
    hipLaunchKernelGGL(delta_scan, dim3(B), dim3(256), 0, stream,
                       seq, kn_t, v_t, q_t, w_t, wrp, brp, wout, bout, out);
}

// Round 8
// 262.009 us; speedup vs baseline: 1.1481x; 1.1481x over previous
//
#include <hip/hip_runtime.h>
#include <hip/hip_bf16.h>

#define HH   64
#define H2   128
#define VOC  64
#define LSEQ 2048
#define LAA  1241              // steps 0..1240 scanned directly (waves 0-3)
#define LBB  806               // steps 1241..2046 as affine map (waves 4-7)

typedef float f2 __attribute__((ext_vector_type(2)));
struct K2 { f2 a, b; };
__device__ __forceinline__ K2 as2(float4 q) { return __builtin_bit_cast(K2, q); }

#define P_dotA(X, b0, b1, b2, b3)                                            \
    ((X[0] * b0.a + X[1] * b0.b) + (X[2] * b1.a + X[3] * b1.b) +             \
     (X[4] * b2.a + X[5] * b2.b) + (X[6] * b3.a + X[7] * b3.b))

// ---------------------------------------------------------------------------
// Kernel 1: collapse embed -> FFN -> LN -> {kn, v, q} projections into
// per-token tables (VOCAB=64 entries of H=64 floats each).  (unchanged)
// ---------------------------------------------------------------------------
__global__ __launch_bounds__(128) void build_tables(
    const float* __restrict__ embed, const float* __restrict__ w1, const float* __restrict__ b1,
    const float* __restrict__ w2, const float* __restrict__ b2,
    const float* __restrict__ ln_g, const float* __restrict__ ln_b,
    const float* __restrict__ wk, const float* __restrict__ wv, const float* __restrict__ wq,
    float* __restrict__ kn_t, float* __restrict__ v_t, float* __restrict__ q_t)
{
    const int tok = blockIdx.x;
    const int tid = threadIdx.x;
    __shared__ float e_lds[HH];
    __shared__ float h_lds[H2];
    __shared__ float hs_lds[HH];

    if (tid < HH) e_lds[tid] = embed[tok * HH + tid];
    __syncthreads();

    {
        float s = b1[tid];
        #pragma unroll 8
        for (int i = 0; i < HH; ++i) s = fmaf(e_lds[i], w1[i * H2 + tid], s);
        h_lds[tid] = fmaxf(s, 0.f);
    }
    __syncthreads();

    if (tid < HH) {
        float f = b2[tid];
        #pragma unroll 8
        for (int j = 0; j < H2; ++j) f = fmaf(h_lds[j], w2[j * HH + tid], f);
        float x = e_lds[tid] + f;
        float sum = x, sq = x * x;
        #pragma unroll
        for (int m = 1; m < 64; m <<= 1) { sum += __shfl_xor(sum, m); sq += __shfl_xor(sq, m); }
        float mu  = sum * (1.f / HH);
        float var = sq * (1.f / HH) - mu * mu;
        hs_lds[tid] = (x - mu) * rsqrtf(var + 1e-5f) * ln_g[tid] + ln_b[tid];
    }
    __syncthreads();

    if (tid < HH) {
        float k = 0.f, v = 0.f, q = 0.f;
        #pragma unroll 8
        for (int j = 0; j < HH; ++j) {
            float h = hs_lds[j];
            k = fmaf(h, wk[j * HH + tid], k);
            v = fmaf(h, wv[j * HH + tid], v);
            q = fmaf(h, wq[j * HH + tid], q);
        }
        float kk = k * k;
        #pragma unroll
        for (int m = 1; m < 64; m <<= 1) kk += __shfl_xor(kk, m);
        float kn = k / fmaxf(sqrtf(kk), 1e-12f);
        kn_t[tok * HH + tid] = kn;
        v_t [tok * HH + tid] = v;
        q_t [tok * HH + tid] = q;
    }
}

// ---------------------------------------------------------------------------
// Kernel 1b: W[a][b] = kn_a . kn_b  (64x64 token-pair dot table, unchanged)
// ---------------------------------------------------------------------------
__global__ __launch_bounds__(64) void build_w(
    const float* __restrict__ kn_t, float* __restrict__ w_t)
{
    const int a = blockIdx.x, b = threadIdx.x;
    __shared__ float ka[HH];
    ka[b] = kn_t[a * HH + b];
    __syncthreads();
    const float4* kav = (const float4*)ka;
    const float4* kbv = (const float4*)(kn_t + b * HH);
    float4 s = {0.f, 0.f, 0.f, 0.f};
    #pragma unroll
    for (int j = 0; j < 16; ++j) {
        float4 x = kav[j], y = kbv[j];
        s.x = fmaf(x.x, y.x, s.x); s.y = fmaf(x.y, y.y, s.y);
        s.z = fmaf(x.z, y.z, s.z); s.w = fmaf(x.w, y.w, s.w);
    }
    w_t[a * VOC + b] = (s.x + s.y) + (s.z + s.w);
}

// ---------------------------------------------------------------------------
// Kernel 2: split-affine lag-1 WY scan, 512 threads = 8 waves = 2 waves/SIMD.
//  waves 0-3: M-scan of steps 0..LAA-1 (lag-1 WY, round-6 structure)
//  waves 4-7: affine map (P,Q) of steps LAA..2046:
//      X_t = X_{t-1} - (X_{t-1}k_t - b_t)k_t^T ; P: b=0, X0=I ; Q: b=v, X0=0
//  Epilogue: r = M_A (P q) + Q q  (M_final never materialized).
// ---------------------------------------------------------------------------
__device__ __forceinline__ float quad_sum(float p) {
    int q = __builtin_amdgcn_mov_dpp(__builtin_bit_cast(int, p), 0xB1, 0xF, 0xF, true);
    p += __builtin_bit_cast(float, q);
    q = __builtin_amdgcn_mov_dpp(__builtin_bit_cast(int, p), 0x4E, 0xF, 0xF, true);
    p += __builtin_bit_cast(float, q);
    return p;
}

#define BODYA(u)                                                             \
{                                                                            \
    const int sp = ((u) + 6) & 7;                                            \
    const int sc = ((u) + 1) & 7;                                            \
    Tq[((u) + 2) & 7] = seq_lds[nb + (u) + 10];                              \
    const int th = Tq[((u) + 6) & 7];                                        \
    const int tl = Tq[((u) + 5) & 7];                                        \
    const float4* kp = kn4 + th * 16 + j0q;                                  \
    Kb[sp][0] = kp[0]; Kb[sp][1] = kp[1]; Kb[sp][2] = kp[2]; Kb[sp][3] = kp[3]; \
    vb[sp] = v_lds[th * HH + i];                                             \
    wb[sp] = w_lds[tl * VOC + th];                                           \
    K2 a0 = as2(Kb[sc][0]), a1 = as2(Kb[sc][1]);                             \
    K2 a2 = as2(Kb[sc][2]), a3 = as2(Kb[sc][3]);                             \
    f2 c0 = M2[0] * a0.a + M2[4] * a2.a;                                     \
    f2 c1 = M2[1] * a0.b + M2[5] * a2.b;                                     \
    f2 c2 = M2[2] * a1.a + M2[6] * a3.a;                                     \
    f2 c3 = M2[3] * a1.b + M2[7] * a3.b;                                     \
    K2 u0 = as2(Kb[(u)][0]), u1 = as2(Kb[(u)][1]);                           \
    K2 u2 = as2(Kb[(u)][2]), u3 = as2(Kb[(u)][3]);                           \
    f2 dv = {dP, dP};                                                        \
    M2[0] += dv * u0.a; M2[1] += dv * u0.b;                                  \
    M2[2] += dv * u1.a; M2[3] += dv * u1.b;                                  \
    M2[4] += dv * u2.a; M2[5] += dv * u2.b;                                  \
    M2[6] += dv * u3.a; M2[7] += dv * u3.b;                                  \
    f2 cc = (c0 + c1) + (c2 + c3);                                           \
    float rawp = quad_sum(cc[0] + cc[1]);                                    \
    dP = vb[sc] - fmaf(dP, wb[sc], rawp);                                    \
}

#define BODYB(u)                                                             \
{                                                                            \
    const int sp = ((u) + 6) & 7;                                            \
    const int sc = ((u) + 1) & 7;                                            \
    Tq[((u) + 2) & 7] = seq_lds[nb + (u) + 10];                              \
    const int th = Tq[((u) + 6) & 7];                                        \
    const int tl = Tq[((u) + 5) & 7];                                        \
    const float4* kp = kn4 + th * 16 + j0q;                                  \
    Kb[sp][0] = kp[0]; Kb[sp][1] = kp[1]; Kb[sp][2] = kp[2]; Kb[sp][3] = kp[3]; \
    vb[sp] = v_lds[th * HH + i];                                             \
    wb[sp] = w_lds[tl * VOC + th];                                           \
    K2 a0 = as2(Kb[sc][0]), a1 = as2(Kb[sc][1]);                             \
    K2 a2 = as2(Kb[sc][2]), a3 = as2(Kb[sc][3]);                             \
    f2 p0 = P2[0] * a0.a + P2[4] * a2.a;                                     \
    f2 p1 = P2[1] * a0.b + P2[5] * a2.b;                                     \
    f2 p2 = P2[2] * a1.a + P2[6] * a3.a;                                     \
    f2 p3 = P2[3] * a1.b + P2[7] * a3.b;                                     \
    f2 q0 = Q2[0] * a0.a + Q2[4] * a2.a;                                     \
    f2 q1 = Q2[1] * a0.b + Q2[5] * a2.b;                                     \
    f2 q2 = Q2[2] * a1.a + Q2[6] * a3.a;                                     \
    f2 q3 = Q2[3] * a1.b + Q2[7] * a3.b;                                     \
    K2 u0 = as2(Kb[(u)][0]), u1 = as2(Kb[(u)][1]);                           \
    K2 u2 = as2(Kb[(u)][2]), u3 = as2(Kb[(u)][3]);                           \
    f2 dpv = {eP, eP};                                                       \
    f2 dqv = {eQ, eQ};                                                       \
    P2[0] += dpv * u0.a; P2[1] += dpv * u0.b;                                \
    P2[2] += dpv * u1.a; P2[3] += dpv * u1.b;                                \
    P2[4] += dpv * u2.a; P2[5] += dpv * u2.b;                                \
    P2[6] += dpv * u3.a; P2[7] += dpv * u3.b;                                \
    Q2[0] += dqv * u0.a; Q2[1] += dqv * u0.b;                                \
    Q2[2] += dqv * u1.a; Q2[3] += dqv * u1.b;                                \
    Q2[4] += dqv * u2.a; Q2[5] += dqv * u2.b;                                \
    Q2[6] += dqv * u3.a; Q2[7] += dqv * u3.b;                                \
    f2 pp = (p0 + p1) + (p2 + p3);                                           \
    f2 qq = (q0 + q1) + (q2 + q3);                                           \
    float rawP = quad_sum(pp[0] + pp[1]);                                    \
    float rawQ = quad_sum(qq[0] + qq[1]);                                    \
    eP = -fmaf(eP, wb[sc], rawP);                                            \
    eQ = vb[sc] - fmaf(eQ, wb[sc], rawQ);                                    \
}

__global__ __launch_bounds__(512) void delta_scan(
    const int* __restrict__ seq,
    const float* __restrict__ kn_t, const float* __restrict__ v_t, const float* __restrict__ q_t,
    const float* __restrict__ w_t,
    const float* __restrict__ wrp, const float* __restrict__ brp,
    const float* __restrict__ wout, const float* __restrict__ bout,
    float* __restrict__ out)
{
    __shared__ __align__(64) float kn_lds[VOC * HH];
    __shared__ __align__(64) float v_lds[VOC * HH];
    __shared__ __align__(64) float w_lds[VOC * VOC];
    __shared__ __align__(16) int   seq_lds[LSEQ + 8];
    __shared__ float uP_lds[HH];
    __shared__ float uQ_lds[HH];
    __shared__ float r_lds[HH];
    __shared__ float t_lds[HH];

    const int b   = blockIdx.x;
    const int tid = threadIdx.x;

    {
        const float4* s1 = (const float4*)kn_t; float4* d1 = (float4*)kn_lds;
        const float4* s2 = (const float4*)v_t;  float4* d2 = (float4*)v_lds;
        const float4* s4 = (const float4*)w_t;  float4* d4 = (float4*)w_lds;
        #pragma unroll
        for (int r = 0; r < 2; ++r) {
            d1[tid + 512 * r] = s1[tid + 512 * r];
            d2[tid + 512 * r] = s2[tid + 512 * r];
            d4[tid + 512 * r] = s4[tid + 512 * r];
        }
        const int4* s3 = (const int4*)(seq + (long)b * LSEQ);
        ((int4*)seq_lds)[tid] = s3[tid];
        if (tid < 8) seq_lds[LSEQ + tid] = 0;   // pads: reads reach [2055]
    }
    __syncthreads();

    const int lt  = tid & 255;
    const int i   = lt >> 2;
    const int j0  = (lt & 3) * 16;
    const int j0q = j0 >> 2;
    const float4* kn4 = (const float4*)kn_lds;

    float4 Kb[8][4];
    float  vb[8], wb[8];
    int    Tq[8];

    if (tid < 256) {
        // ===== waves 0-3: direct M-scan of steps 0..LAA-1 =====
        f2 M2[8];
        #pragma unroll
        for (int n = 0; n < 8; ++n) M2[n] = (f2){0.f, 0.f};

        const int t0 = seq_lds[0], t1 = seq_lds[1], t2 = seq_lds[2];
        const int t3 = seq_lds[3], t4 = seq_lds[4], t5 = seq_lds[5];
        Tq[5] = t5;          Tq[6] = seq_lds[6];  Tq[7] = seq_lds[7];
        Tq[0] = seq_lds[8];  Tq[1] = seq_lds[9];
        {
            const int pt[6] = {t0, t1, t2, t3, t4, t5};
            #pragma unroll
            for (int s = 0; s < 6; ++s) {
                const float4* kp = kn4 + pt[s] * 16 + j0q;
                Kb[s][0] = kp[0]; Kb[s][1] = kp[1]; Kb[s][2] = kp[2]; Kb[s][3] = kp[3];
            }
            #pragma unroll
            for (int s = 1; s < 6; ++s) {
                vb[s] = v_lds[pt[s] * HH + i];
                wb[s] = w_lds[pt[s - 1] * VOC + pt[s]];
            }
        }
        float dP = v_lds[t0 * HH + i];      // e_0 = v_0 (M_{-1} = 0)

        int nb = 0;
        for (int g = 0; g < 155; ++g) {     // iters 0..1239
            BODYA(0) BODYA(1) BODYA(2) BODYA(3)
            BODYA(4) BODYA(5) BODYA(6) BODYA(7)
            nb += 8;
        }
        {   // final pending update: step 1240, slot 0
            K2 u0 = as2(Kb[0][0]), u1 = as2(Kb[0][1]);
            K2 u2 = as2(Kb[0][2]), u3 = as2(Kb[0][3]);
            f2 dv = {dP, dP};
            M2[0] += dv * u0.a; M2[1] += dv * u0.b;
            M2[2] += dv * u1.a; M2[3] += dv * u1.b;
            M2[4] += dv * u2.a; M2[5] += dv * u2.b;
            M2[6] += dv * u3.a; M2[7] += dv * u3.b;
        }
        __syncthreads();   // uP/uQ ready

        {
            const float4* up4 = (const float4*)&uP_lds[j0];
            K2 b0 = as2(up4[0]), b1 = as2(up4[1]);
            K2 b2 = as2(up4[2]), b3 = as2(up4[3]);
            f2 s = P_dotA(M2, b0, b1, b2, b3);
            float p = quad_sum(s[0] + s[1]);
            if ((lt & 3) == 0) r_lds[i] = p + uQ_lds[i];
        }
    } else {
        // ===== waves 4-7: affine map (P,Q) of steps LAA..2046 =====
        f2 P2[8], Q2[8];
        #pragma unroll
        for (int n = 0; n < 8; ++n) {
            int j = j0 + 2 * n;
            f2 z = {0.f, 0.f};
            if (j     == i) z[0] = 1.f;
            if (j + 1 == i) z[1] = 1.f;
            P2[n] = z;
            Q2[n] = (f2){0.f, 0.f};
        }

        const int m0 = seq_lds[LAA + 0], m1 = seq_lds[LAA + 1], m2 = seq_lds[LAA + 2];
        const int m3 = seq_lds[LAA + 3], m4 = seq_lds[LAA + 4], m5 = seq_lds[LAA + 5];
        Tq[5] = m5;                Tq[6] = seq_lds[LAA + 6];  Tq[7] = seq_lds[LAA + 7];
        Tq[0] = seq_lds[LAA + 8];  Tq[1] = seq_lds[LAA + 9];
        {
            const int pt[6] = {m0, m1, m2, m3, m4, m5};
            #pragma unroll
            for (int s = 0; s < 6; ++s) {
                const float4* kp = kn4 + pt[s] * 16 + j0q;
                Kb[s][0] = kp[0]; Kb[s][1] = kp[1]; Kb[s][2] = kp[2]; Kb[s][3] = kp[3];
            }
            #pragma unroll
            for (int s = 1; s < 6; ++s) {
                vb[s] = v_lds[pt[s] * HH + i];
                wb[s] = w_lds[pt[s - 1] * VOC + pt[s]];
            }
        }
        float eP = -kn_lds[m0 * HH + i];    // e_P0 = -(I k)
        float eQ =  v_lds[m0 * HH + i];     // e_Q0 = v

        int nb = LAA;
        for (int g = 0; g < 100; ++g) {     // local iters 0..799
            BODYB(0) BODYB(1) BODYB(2) BODYB(3)
            BODYB(4) BODYB(5) BODYB(6) BODYB(7)
            nb += 8;
        }
        BODYB(0) BODYB(1) BODYB(2) BODYB(3) BODYB(4)   // local iters 800..804
        {   // final pending update: local step 805, slot 5
            K2 u0 = as2(Kb[5][0]), u1 = as2(Kb[5][1]);
            K2 u2 = as2(Kb[5][2]), u3 = as2(Kb[5][3]);
            f2 dpv = {eP, eP}, dqv = {eQ, eQ};
            P2[0] += dpv * u0.a; P2[1] += dpv * u0.b;
            P2[2] += dpv * u1.a; P2[3] += dpv * u1.b;
            P2[4] += dpv * u2.a; P2[5] += dpv * u2.b;
            P2[6] += dpv * u3.a; P2[7] += dpv * u3.b;
            Q2[0] += dqv * u0.a; Q2[1] += dqv * u0.b;
            Q2[2] += dqv * u1.a; Q2[3] += dqv * u1.b;
            Q2[4] += dqv * u2.a; Q2[5] += dqv * u2.b;
            Q2[6] += dqv * u3.a; Q2[7] += dqv * u3.b;
        }

        {
            const int qtok = seq_lds[LSEQ - 1];
            const float4* q4 = (const float4*)(q_t + (long)qtok * HH + j0);
            float4 qa = q4[0], qb = q4[1], qc = q4[2], qd = q4[3];
            K2 b0 = as2(qa), b1 = as2(qb), b2 = as2(qc), b3 = as2(qd);
            f2 sp = P_dotA(P2, b0, b1, b2, b3);
            f2 sq = P_dotA(Q2, b0, b1, b2, b3);
            float pv = quad_sum(sp[0] + sp[1]);
            float qv = quad_sum(sq[0] + sq[1]);
            if ((lt & 3) == 0) { uP_lds[i] = pv; uQ_lds[i] = qv; }
        }
        __syncthreads();
    }
    __syncthreads();

    if (tid < HH) {
        float s = brp[tid];
        #pragma unroll 8
        for (int ii = 0; ii < HH; ++ii) s = fmaf(r_lds[ii], wrp[ii * HH + tid], s);
        t_lds[tid] = s;
    }
    __syncthreads();

    if (tid < HH) {
        float s = bout[tid];
        #pragma unroll 8
        for (int h = 0; h < HH; ++h) s = fmaf(t_lds[h], wout[h * VOC + tid], s);
        out[(long)b * VOC + tid] = s;
    }
}

extern "C" void kernel_launch(void* const* d_in, const int* in_sizes, int n_in,
                              void* d_out, int out_size, void* d_ws, size_t ws_size,
                              hipStream_t stream)
{
    const int*   seq   = (const int*)  d_in[0];
    const float* embed = (const float*)d_in[1];
    const float* w1    = (const float*)d_in[2];
    const float* b1    = (const float*)d_in[3];
    const float* w2    = (const float*)d_in[4];
    const float* b2    = (const float*)d_in[5];
    const float* ln_g  = (const float*)d_in[6];
    const float* ln_b  = (const float*)d_in[7];
    const float* wk    = (const float*)d_in[8];
    const float* wv    = (const float*)d_in[9];
    const float* wq    = (const float*)d_in[10];
    const float* wrp   = (const float*)d_in[11];
    const float* brp   = (const float*)d_in[12];
    const float* wout  = (const float*)d_in[13];
    const float* bout  = (const float*)d_in[14];
    float* out = (float*)d_out;

    float* kn_t = (float*)d_ws;
    float* v_t  = kn_t + VOC * HH;
    float* q_t  = v_t  + VOC * HH;
    float* w_t  = q_t  + VOC * HH;

    const int B = in_sizes[0] / LSEQ;   // 256

    hipLaunchKernelGGL(build_tables, dim3(VOC), dim3(H2), 0, stream,
                       embed, w1, b1, w2, b2, ln_g, ln_b, wk, wv, wq,
                       kn_t, v_t, q_t);
    hipLaunchKernelGGL(build_w, dim3(VOC), dim3(HH), 0, stream, kn_t, w_t);
    hipLaunchKernelGGL(delta_scan, dim3(B), dim3(512), 0, stream,
                       seq, kn_t, v_t, q_t, w_t, wrp, brp, wout, bout, out);
}